// Round 1
// 329.718 us; speedup vs baseline: 1.0299x; 1.0299x over previous
//
#include <hip/hip_runtime.h>
#include <hip/hip_bf16.h>

typedef __attribute__((ext_vector_type(8))) short short8_t;
typedef __attribute__((ext_vector_type(4))) float floatx4;
typedef unsigned short ushort_t;
typedef unsigned int uint_t;

#define RSTR 72        // shorts per tile column (9 x 16B chunks; odd -> spread banks)
#define TSZ  (132 * RSTR)  // shorts per x-row tile (cols 0..131)

__device__ __forceinline__ uint_t rne_u(float f) {
    uint_t u = __float_as_uint(f);
    return u + (0x7fffu + ((u >> 16) & 1u));   // bf16(f) in bits[31:16], RNE
}
__device__ __forceinline__ uint_t pk2(float lo, float hi) {
    return __builtin_amdgcn_perm(rne_u(hi), rne_u(lo), 0x07060302u);
}

// one-time transpose/convert: w2[co][khw*64+ci] = bf16(w[co][ci*9+khw])
__global__ void w2_prepass(const float* __restrict__ w, ushort_t* __restrict__ w2) {
    int idx = blockIdx.x * 256 + threadIdx.x;  // exactly 73728
    int co  = idx / 576;
    int k   = idx - co * 576;
    int khw = k >> 6, ci = k & 63;
    w2[idx] = (ushort_t)(rne_u(w[co * 576 + ci * 9 + khw]) >> 16);
}

// Block = 2 output rows (ho0, ho0+1) x 128 wo x 128 co. 512 threads = 8 waves.
// Staging is pipelined 2 rows deep (dva/dvb, 32 VGPRs peak) to fit the
// 128-unified-reg budget of __launch_bounds__(512,4) WITHOUT scratch spills
// (previous version staged all 4 rows -> 64 VGPRs + 64 AGPRs + temps -> 135 MB
// of scratch writes per dispatch). B fragments are loaded per-round from the
// L2-hot w2 (147 KB shared by all blocks); the fully-unrolled 18-round loop
// gives the scheduler freedom to hoist them as register pressure allows.
__global__ __launch_bounds__(512, 4)
void conv_min_tanh_kernel(const float* __restrict__ x,
                          const float* __restrict__ w,
                          const ushort_t* __restrict__ w2,
                          const float* __restrict__ bias,
                          float* __restrict__ out,
                          int use_w2)
{
    __shared__ ushort_t T[4 * TSZ];    // 76,032 B
    __shared__ float red[2][256];      // 2,048 B

    const int tid  = threadIdx.x;
    const int bid  = blockIdx.x;
    const int n    = bid / 63;
    const int ho0  = (bid - n * 63) * 2;

    const int tx = tid & 31;   // cols 4tx..4tx+3
    const int ty = tid >> 5;   // ci 4ty..4ty+3 (0..15)

    const int lane = tid & 63;
    const int wid  = tid >> 6;         // 0..7
    const int wm   = wid >> 1;         // m-quarter (64 rows each; wm>>1 = out-row)
    const int wn   = wid & 1;          // co-half
    const int r16  = lane & 15;
    const int quad = lane >> 4;

    const float* xbase = x + ((size_t)n << 20) + (size_t)ho0 * 128;

    auto load_row = [&](floatx4 (&dv)[4], const int s) {
#pragma unroll
        for (int j = 0; j < 4; ++j)
            dv[j] = *reinterpret_cast<const floatx4*>(
                xbase + (size_t)(ty * 4 + j) * 16384 + s * 128 + tx * 4);
    };
    auto conv_row = [&](floatx4 (&dv)[4], const int s) {
#pragma unroll
        for (int i = 0; i < 4; ++i) {
            uint2 u;
            u.x = pk2(dv[0][i], dv[1][i]);   // ci 4ty, 4ty+1
            u.y = pk2(dv[2][i], dv[3][i]);   // ci 4ty+2, 4ty+3
            const int c   = tx * 4 + i;
            const int swz = (ty >> 1) ^ ((c >> 3) & 7);   // 16B-chunk xor swizzle
            *reinterpret_cast<uint2*>(&T[s * TSZ + c * RSTR + swz * 8 + (ty & 1) * 4]) = u;
        }
    };

    // ---- pipelined staging: 2 rows in flight (32 VGPRs), no spills ----
    floatx4 dva[4], dvb[4];
    load_row(dva, 0);
    load_row(dvb, 1);

    // zero pad cols 128..131 of each tile while loads fly
    for (int idx = tid; idx < 576; idx += 512) {
        int s = idx / 144, o = idx - s * 144;
        reinterpret_cast<uint_t*>(T)[s * (TSZ / 2) + (128 * RSTR) / 2 + o] = 0u;
    }

    conv_row(dva, 0);
    load_row(dva, 2);
    conv_row(dvb, 1);
    load_row(dvb, 3);
    conv_row(dva, 2);
    conv_row(dvb, 3);

    floatx4 acc[4][4];
#pragma unroll
    for (int i = 0; i < 4; ++i)
#pragma unroll
        for (int j = 0; j < 4; ++j)
            acc[i][j] = (floatx4){0.f, 0.f, 0.f, 0.f};

    const ushort_t* w2base = w2 + (size_t)(wn * 64 + r16) * 576 + quad * 8;
    const float*    wbase  = w + (size_t)(wn * 64 + r16) * 576;  // fallback

    __syncthreads();  // all tiles ready; the only staging barrier

    // ---- 18 rounds: kh(0..2) x kw(0..2) x ci-half(0..1), K=32 each ----
#pragma unroll
    for (int rd = 0; rd < 18; ++rd) {
        const int khw  = rd >> 1;           // kh*3+kw
        const int kh   = khw / 3;
        const int kw   = khw - kh * 3;
        const int half = rd & 1;

        // B fragments for this round (L2-hot; compiler schedules/hoists)
        short8_t bfr[4];
        if (use_w2) {
            const ushort_t* bb = w2base + khw * 64 + half * 32;
#pragma unroll
            for (int t4 = 0; t4 < 4; ++t4)
                bfr[t4] = *reinterpret_cast<const short8_t*>(bb + (size_t)t4 * (16 * 576));
        } else {
#pragma unroll
            for (int t4 = 0; t4 < 4; ++t4) {
                const float* wp = wbase + (size_t)t4 * (16 * 576)
                                + (size_t)(half * 32 + quad * 8) * 9 + khw;
                short8_t b;
#pragma unroll
                for (int q = 0; q < 4; ++q) {
                    uint_t u = pk2(wp[(2 * q) * 9], wp[(2 * q + 1) * 9]);
                    b[2 * q]     = (short)(u & 0xffffu);
                    b[2 * q + 1] = (short)(u >> 16);
                }
                bfr[t4] = b;
            }
        }

        // A fragments from LDS: m = wm*64 + t4*16 + r16 -> out-row m>>7, wo m&127
        short8_t afr[4];
#pragma unroll
        for (int t4 = 0; t4 < 4; ++t4) {
            const int m  = wm * 64 + t4 * 16 + r16;
            const int s  = (m >> 7) + kh;
            const int c  = (m & 127) + kw;
            const int sw = (half * 4 + quad) ^ ((c >> 3) & 7);
            afr[t4] = *reinterpret_cast<const short8_t*>(&T[s * TSZ + c * RSTR + sw * 8]);
        }
#pragma unroll
        for (int tm = 0; tm < 4; ++tm)
#pragma unroll
            for (int tn = 0; tn < 4; ++tn)
                acc[tm][tn] = __builtin_amdgcn_mfma_f32_16x16x32_bf16(
                    afr[tm], bfr[tn], acc[tm][tn], 0, 0, 0);
    }

    // ---- epilogue: +bias, min over co, cross-lane/wave min, tanh(tanh) ----
    float bvv[4];
#pragma unroll
    for (int tn = 0; tn < 4; ++tn)
        bvv[tn] = bias[wn * 64 + tn * 16 + r16];

#pragma unroll
    for (int tm = 0; tm < 4; ++tm) {
#pragma unroll
        for (int r = 0; r < 4; ++r) {
            // C/D: row(m) = quad*4 + r, col(co) = r16
            float v = acc[tm][0][r] + bvv[0];
            v = fminf(v, acc[tm][1][r] + bvv[1]);
            v = fminf(v, acc[tm][2][r] + bvv[2]);
            v = fminf(v, acc[tm][3][r] + bvv[3]);
            v = fminf(v, __shfl_xor(v, 1, 64));
            v = fminf(v, __shfl_xor(v, 2, 64));
            v = fminf(v, __shfl_xor(v, 4, 64));
            v = fminf(v, __shfl_xor(v, 8, 64));
            if (r16 == 0)
                red[wn][wm * 64 + tm * 16 + quad * 4 + r] = v;
        }
    }
    __syncthreads();

    if (tid < 256) {
        const int r  = tid >> 7;       // out-row within pair
        const int wo = tid & 127;
        if (wo < 126) {
            float v = fminf(red[0][tid], red[1][tid]);
            v = tanhf(tanhf(v));
            out[((size_t)n * 126 + ho0 + r) * 126 + wo] = v;
        }
    }
}

extern "C" void kernel_launch(void* const* d_in, const int* in_sizes, int n_in,
                              void* d_out, int out_size, void* d_ws, size_t ws_size,
                              hipStream_t stream) {
    const float* x    = (const float*)d_in[0];   // [32,64,128,128] f32
    const float* w    = (const float*)d_in[1];   // [128,64,3,3] f32
    const float* bias = (const float*)d_in[2];   // [128] f32
    float* out = (float*)d_out;                  // [32,1,126,126] f32

    const int use_w2 = (ws_size >= (size_t)(73728 * 2)) ? 1 : 0;
    ushort_t* w2 = (ushort_t*)d_ws;

    if (use_w2)
        w2_prepass<<<dim3(288), dim3(256), 0, stream>>>(w, w2);

    // 32 images x 63 row-pairs = 2016 blocks
    conv_min_tanh_kernel<<<dim3(2016), dim3(512), 0, stream>>>(x, w, w2, bias, out, use_w2);
}

// Round 2
// 276.217 us; speedup vs baseline: 1.2294x; 1.1937x over previous
//
#include <hip/hip_runtime.h>
#include <hip/hip_bf16.h>

typedef __attribute__((ext_vector_type(8))) short short8_t;
typedef __attribute__((ext_vector_type(4))) float floatx4;
typedef unsigned short ushort_t;
typedef unsigned int uint_t;

#define RSTR 72        // shorts per tile column (9 x 16B chunks; odd -> spread banks)
#define TSZ  (132 * RSTR)  // shorts per x-row tile (cols 0..131)

__device__ __forceinline__ uint_t rne_u(float f) {
    uint_t u = __float_as_uint(f);
    return u + (0x7fffu + ((u >> 16) & 1u));   // bf16(f) in bits[31:16], RNE
}
__device__ __forceinline__ uint_t pk2(float lo, float hi) {
    return __builtin_amdgcn_perm(rne_u(hi), rne_u(lo), 0x07060302u);
}

// one-time transpose/convert, NEW layout: w2[rd][co][c32] with rd = khw*2+half,
// ci = half*32+c32; value = bf16(w[co][ci][kh][kw]).
// Per-thread B fragment per round is then ONE base + small immediate offsets:
//   off(rd,co,quad) = rd*4096 + co*32 + quad*8 shorts; t4 stride = 1024 B (imm-able).
__global__ void w2_prepass(const float* __restrict__ w, ushort_t* __restrict__ w2) {
    int idx = blockIdx.x * 256 + threadIdx.x;  // exactly 73728 = 18*128*32
    int rd  = idx >> 12;           // 0..17
    int rem = idx & 4095;
    int co  = rem >> 5;
    int c32 = rem & 31;
    int khw = rd >> 1, half = rd & 1;
    int ci  = half * 32 + c32;
    w2[idx] = (ushort_t)(rne_u(w[co * 576 + ci * 9 + khw]) >> 16);
}

// Block = 2 output rows x 128 wo x 128 co. 512 threads = 8 waves.
// USE_W2 is a TEMPLATE param: the hot instantiation has no fallback path
// (the runtime use_w2 branch kept both paths' register pressure live and
// caused persistent scratch spills -> 86 MB WRITE_SIZE).
template<bool USE_W2>
__global__ __launch_bounds__(512, 4)
void conv_min_tanh_kernel(const float* __restrict__ x,
                          const float* __restrict__ w,
                          const ushort_t* __restrict__ w2,
                          const float* __restrict__ bias,
                          float* __restrict__ out)
{
    __shared__ ushort_t T[4 * TSZ];    // 76,032 B
    __shared__ float red[2][256];      // 2,048 B

    const int tid  = threadIdx.x;
    // XCD-aware swizzle: 2016 blocks = 8 XCDs x 252. HW maps bid%8 -> XCD, so
    // work = (bid%8)*252 + bid/8 gives each XCD a CONTIGUOUS run of row-pairs;
    // adjacent blocks share 2 of their 4 x-rows -> L2-local refetch.
    const int bid0 = blockIdx.x;
    const int bid  = (bid0 & 7) * 252 + (bid0 >> 3);
    const int n    = bid / 63;
    const int ho0  = (bid - n * 63) * 2;

    const int tx = tid & 31;   // cols 4tx..4tx+3
    const int ty = tid >> 5;   // ci 4ty..4ty+3 (0..15)

    const int lane = tid & 63;
    const int wid  = tid >> 6;         // 0..7
    const int wm   = wid >> 1;         // m-quarter (64 rows each; wm>>1 = out-row)
    const int wn   = wid & 1;          // co-half
    const int r16  = lane & 15;
    const int quad = lane >> 4;

    const float* xbase = x + ((size_t)n << 20) + (size_t)ho0 * 128;

    auto load_row = [&](floatx4 (&dv)[4], const int s) {
#pragma unroll
        for (int j = 0; j < 4; ++j)
            dv[j] = *reinterpret_cast<const floatx4*>(
                xbase + (size_t)(ty * 4 + j) * 16384 + s * 128 + tx * 4);
    };
    auto conv_row = [&](floatx4 (&dv)[4], const int s) {
#pragma unroll
        for (int i = 0; i < 4; ++i) {
            uint2 u;
            u.x = pk2(dv[0][i], dv[1][i]);   // ci 4ty, 4ty+1
            u.y = pk2(dv[2][i], dv[3][i]);   // ci 4ty+2, 4ty+3
            const int c   = tx * 4 + i;
            const int swz = (ty >> 1) ^ ((c >> 3) & 7);   // 16B-chunk xor swizzle
            *reinterpret_cast<uint2*>(&T[s * TSZ + c * RSTR + swz * 8 + (ty & 1) * 4]) = u;
        }
    };

    // ---- pipelined staging: 2 rows in flight (32 VGPRs), no spills ----
    floatx4 dva[4], dvb[4];
    load_row(dva, 0);
    load_row(dvb, 1);

    // zero pad cols 128..131 of each tile while loads fly
    for (int idx = tid; idx < 576; idx += 512) {
        int s = idx / 144, o = idx - s * 144;
        reinterpret_cast<uint_t*>(T)[s * (TSZ / 2) + (128 * RSTR) / 2 + o] = 0u;
    }

    conv_row(dva, 0);
    load_row(dva, 2);
    conv_row(dvb, 1);
    load_row(dvb, 3);
    conv_row(dva, 2);
    conv_row(dvb, 3);

    floatx4 acc[4][4];
#pragma unroll
    for (int i = 0; i < 4; ++i)
#pragma unroll
        for (int j = 0; j < 4; ++j)
            acc[i][j] = (floatx4){0.f, 0.f, 0.f, 0.f};

    // ONE B base pointer; per-round offset rd*8192 B, per-t4 offset t4*1024 B.
    const ushort_t* w2base = w2 + (size_t)(wn * 64 + r16) * 32 + quad * 8;
    const float*    wbase  = w + (size_t)(wn * 64 + r16) * 576;  // fallback only

    __syncthreads();  // all tiles ready; the only staging barrier

    // ---- 18 rounds: kh(0..2) x kw(0..2) x ci-half(0..1), K=32 each ----
#pragma unroll
    for (int rd = 0; rd < 18; ++rd) {
        const int khw  = rd >> 1;           // kh*3+kw
        const int kh   = khw / 3;
        const int kw   = khw - kh * 3;
        const int half = rd & 1;

        // B fragments for this round (L2-hot w2, 147 KB shared by all blocks)
        short8_t bfr[4];
        if (USE_W2) {
            const ushort_t* bb = w2base + rd * 4096;
#pragma unroll
            for (int t4 = 0; t4 < 4; ++t4)
                bfr[t4] = *reinterpret_cast<const short8_t*>(bb + t4 * 512);
        } else {
#pragma unroll
            for (int t4 = 0; t4 < 4; ++t4) {
                const float* wp = wbase + (size_t)t4 * (16 * 576)
                                + (size_t)(half * 32 + quad * 8) * 9 + khw;
                short8_t b;
#pragma unroll
                for (int q = 0; q < 4; ++q) {
                    uint_t u = pk2(wp[(2 * q) * 9], wp[(2 * q + 1) * 9]);
                    b[2 * q]     = (short)(u & 0xffffu);
                    b[2 * q + 1] = (short)(u >> 16);
                }
                bfr[t4] = b;
            }
        }

        // A fragments from LDS: m = wm*64 + t4*16 + r16 -> out-row m>>7, wo m&127
        short8_t afr[4];
#pragma unroll
        for (int t4 = 0; t4 < 4; ++t4) {
            const int m  = wm * 64 + t4 * 16 + r16;
            const int s  = (m >> 7) + kh;
            const int c  = (m & 127) + kw;
            const int sw = (half * 4 + quad) ^ ((c >> 3) & 7);
            afr[t4] = *reinterpret_cast<const short8_t*>(&T[s * TSZ + c * RSTR + sw * 8]);
        }
#pragma unroll
        for (int tm = 0; tm < 4; ++tm)
#pragma unroll
            for (int tn = 0; tn < 4; ++tn)
                acc[tm][tn] = __builtin_amdgcn_mfma_f32_16x16x32_bf16(
                    afr[tm], bfr[tn], acc[tm][tn], 0, 0, 0);
    }

    // ---- epilogue: +bias, min over co, cross-lane/wave min, tanh(tanh) ----
    float bvv[4];
#pragma unroll
    for (int tn = 0; tn < 4; ++tn)
        bvv[tn] = bias[wn * 64 + tn * 16 + r16];

#pragma unroll
    for (int tm = 0; tm < 4; ++tm) {
#pragma unroll
        for (int r = 0; r < 4; ++r) {
            // C/D: row(m) = quad*4 + r, col(co) = r16
            float v = acc[tm][0][r] + bvv[0];
            v = fminf(v, acc[tm][1][r] + bvv[1]);
            v = fminf(v, acc[tm][2][r] + bvv[2]);
            v = fminf(v, acc[tm][3][r] + bvv[3]);
            v = fminf(v, __shfl_xor(v, 1, 64));
            v = fminf(v, __shfl_xor(v, 2, 64));
            v = fminf(v, __shfl_xor(v, 4, 64));
            v = fminf(v, __shfl_xor(v, 8, 64));
            if (r16 == 0)
                red[wn][wm * 64 + tm * 16 + quad * 4 + r] = v;
        }
    }
    __syncthreads();

    if (tid < 256) {
        const int r  = tid >> 7;       // out-row within pair
        const int wo = tid & 127;
        if (wo < 126) {
            float v = fminf(red[0][tid], red[1][tid]);
            v = tanhf(tanhf(v));
            out[((size_t)n * 126 + ho0 + r) * 126 + wo] = v;
        }
    }
}

extern "C" void kernel_launch(void* const* d_in, const int* in_sizes, int n_in,
                              void* d_out, int out_size, void* d_ws, size_t ws_size,
                              hipStream_t stream) {
    const float* x    = (const float*)d_in[0];   // [32,64,128,128] f32
    const float* w    = (const float*)d_in[1];   // [128,64,3,3] f32
    const float* bias = (const float*)d_in[2];   // [128] f32
    float* out = (float*)d_out;                  // [32,1,126,126] f32

    const int use_w2 = (ws_size >= (size_t)(73728 * 2)) ? 1 : 0;
    ushort_t* w2 = (ushort_t*)d_ws;

    if (use_w2) {
        w2_prepass<<<dim3(288), dim3(256), 0, stream>>>(w, w2);
        conv_min_tanh_kernel<true><<<dim3(2016), dim3(512), 0, stream>>>(x, w, w2, bias, out);
    } else {
        conv_min_tanh_kernel<false><<<dim3(2016), dim3(512), 0, stream>>>(x, w, w2, bias, out);
    }
}